// Round 17
// baseline (295.830 us; speedup 1.0000x reference)
//
#include <hip/hip_runtime.h>
#include <math.h>

#define SQRT8_INV  0.35355339059327373f   // 1/sqrt(8)
#define H_SCALE    0.04419417382415922f   // 0.25/sqrt(32)
#define FAN_SC     0.04419417382415922f   // 1/sqrt(32*16)
#define W1_SCALE   0.125f                 // 1/sqrt(64)
#define LIN2_SCALE 0.125f                 // 1/sqrt(64)
#define SQ3_INVF   0.57735026918962576f   // 1/sqrt(3)

typedef __attribute__((ext_vector_type(8))) short short8;
typedef __attribute__((ext_vector_type(4))) float f32x4;

__device__ __forceinline__ unsigned pack_bf16(float a, float b) {
    unsigned ua = __float_as_uint(a);
    ua += 0x7FFFu + ((ua >> 16) & 1u);          // RNE
    unsigned ub = __float_as_uint(b);
    ub += 0x7FFFu + ((ub >> 16) & 1u);
    return (ua >> 16) | (ub & 0xFFFF0000u);
}
__device__ __forceinline__ float bf_lo(unsigned u) { return __uint_as_float(u << 16); }
__device__ __forceinline__ float bf_hi(unsigned u) { return __uint_as_float(u & 0xFFFF0000u); }
__device__ __forceinline__ float rl_f(float v, int l) {
    return __uint_as_float(__builtin_amdgcn_readlane(__float_as_uint(v), l));
}

// ---------------- w1 -> w1p (fallback gather path) ----------------
__global__ __launch_bounds__(256) void prep_w1p(const float* __restrict__ w1,
                                                float* __restrict__ w1p) {
    int idx = blockIdx.x * 256 + threadIdx.x;
    if (idx >= 64 * 64) return;
    int j = idx >> 6, t = idx & 63;
    int colA = (t < 32) ? t : t + 32;
    int colB = (t < 32) ? t + 32 : t + 64;
    w1p[idx * 2 + 0] = w1[j * 128 + colA];
    w1p[idx * 2 + 1] = w1[j * 128 + colB];
}

// ---------------- hist (int4) + einfo staging (block-range split) ----------------
// einfo[e] (64 B): [0]=ee[0..3]*s8  [1]=ee[4..7]*s8  [2]=eattr  [3]=pad
__global__ __launch_bounds__(256) void histprep_kernel(
    const int* __restrict__ eidx, int* __restrict__ cnt,
    const float4* __restrict__ ee2, const float4* __restrict__ eattr4,
    uint4* __restrict__ einfo, int E, int nH) {
    if (blockIdx.x < nH) {
        int i = blockIdx.x * 256 + threadIdx.x;
        int base = i * 4;
        if (base + 3 < E) {
            int4 v = ((const int4*)eidx)[i];
            atomicAdd(&cnt[v.x], 1);
            atomicAdd(&cnt[v.y], 1);
            atomicAdd(&cnt[v.z], 1);
            atomicAdd(&cnt[v.w], 1);
        } else {
            for (int e = base; e < E; ++e) atomicAdd(&cnt[eidx[e]], 1);
        }
    } else {
        int e = (blockIdx.x - nH) * 256 + threadIdx.x;
        if (e >= E) return;
        float4 e0 = ee2[(size_t)e * 2], e1 = ee2[(size_t)e * 2 + 1];
        float4 ea = eattr4[e];
        e0.x *= SQRT8_INV; e0.y *= SQRT8_INV; e0.z *= SQRT8_INV; e0.w *= SQRT8_INV;
        e1.x *= SQRT8_INV; e1.y *= SQRT8_INV; e1.z *= SQRT8_INV; e1.w *= SQRT8_INV;
        uint4* r = einfo + (size_t)e * 4;
        r[0] = make_uint4(__float_as_uint(e0.x), __float_as_uint(e0.y),
                          __float_as_uint(e0.z), __float_as_uint(e0.w));
        r[1] = make_uint4(__float_as_uint(e1.x), __float_as_uint(e1.y),
                          __float_as_uint(e1.z), __float_as_uint(e1.w));
        r[2] = make_uint4(__float_as_uint(ea.x), __float_as_uint(ea.y),
                          __float_as_uint(ea.z), __float_as_uint(ea.w));
        r[3] = make_uint4(0u, 0u, 0u, 0u);
    }
}

// ---------------- hierarchical scan, stage A: per-block sums ----------------
__global__ __launch_bounds__(256) void scan_bsum(const int* __restrict__ cnt,
                                                 int* __restrict__ bsum, int N) {
    __shared__ int red[256];
    int t = threadIdx.x, i = blockIdx.x * 256 + t;
    red[t] = (i < N) ? cnt[i] : 0;
    __syncthreads();
    #pragma unroll
    for (int d = 128; d > 0; d >>= 1) {
        if (t < d) red[t] += red[t + d];
        __syncthreads();
    }
    if (t == 0) bsum[blockIdx.x] = red[0];
}

// ---------------- stage B (block 0) + prep_wf (blocks 1..4) ----------------
__global__ __launch_bounds__(1024) void bscan_prep(int* __restrict__ bsum, int nb,
                                                   const float* __restrict__ w1,
                                                   uint4* __restrict__ wf) {
    if (blockIdx.x == 0) {
        __shared__ int s[1024];
        int t = threadIdx.x;
        int v = (t < nb) ? bsum[t] : 0;
        s[t] = v;
        __syncthreads();
        for (int d = 1; d < 1024; d <<= 1) {
            int u = (t >= d) ? s[t - d] : 0;
            __syncthreads();
            s[t] += u;
            __syncthreads();
        }
        if (t < nb) bsum[t] = s[t] - v;   // exclusive
    } else if (threadIdx.x < 256) {
        int idx = (blockIdx.x - 1) * 256 + threadIdx.x;   // 0..1023
        int lane = idx & 63, part = (idx >> 6) & 3, sq = idx >> 8;
        int m = lane & 15, q = lane >> 4;
        int col = sq * 16 + m + ((part & 2) ? 64 : 0);
        int kb  = (part & 1) ? 32 : 0;
        unsigned u[4];
        #pragma unroll
        for (int i2 = 0; i2 < 4; ++i2) {
            float a = w1[(kb + q * 8 + i2 * 2 + 0) * 128 + col];
            float b = w1[(kb + q * 8 + i2 * 2 + 1) * 128 + col];
            unsigned ua = __float_as_uint(a); ua += 0x7FFFu + ((ua >> 16) & 1u);
            unsigned ub = __float_as_uint(b); ub += 0x7FFFu + ((ub >> 16) & 1u);
            u[i2] = (ua >> 16) | (ub & 0xFFFF0000u);
        }
        wf[idx] = make_uint4(u[0], u[1], u[2], u[3]);
    }
}

// ---------------- stage C: in-block scan + base -> off, cur ----------------
__global__ __launch_bounds__(256) void scan_final(const int* __restrict__ cnt,
                                                  const int* __restrict__ bsum,
                                                  int* __restrict__ off,
                                                  int* __restrict__ cur, int N) {
    __shared__ int s[256];
    int t = threadIdx.x, i = blockIdx.x * 256 + t;
    int v = (i < N) ? cnt[i] : 0;
    s[t] = v;
    __syncthreads();
    for (int d = 1; d < 256; d <<= 1) {
        int u = (t >= d) ? s[t - d] : 0;
        __syncthreads();
        s[t] += u;
        __syncthreads();
    }
    int ex = s[t] - v + bsum[blockIdx.x];
    if (i < N) { off[i] = ex; cur[i] = ex; }
    if (i == N - 1) off[N] = ex + v;
}

// ---------------- MERGED slim scatter (16-B record + precomputed flags) + node ----
// rec[pos] = {e, src, dst | cs<<30 | ce<<31, 0}; cs/ce computed from pos's window.
__global__ __launch_bounds__(256) void scatnode_kernel(
    const int* __restrict__ eidx, int* __restrict__ cur,
    const int* __restrict__ off, int4* __restrict__ rec, int E, int nScat,
    const float* __restrict__ nf, const float* __restrict__ attrs,
    const float* __restrict__ l1w0, const float* __restrict__ l1w1,
    const float* __restrict__ scw0, const float* __restrict__ scw1,
    float* __restrict__ h4, float* __restrict__ out, int N) {
    __shared__ float x[2][128];
    __shared__ int vs[2];
    if (blockIdx.x < nScat) {
        // ---------- scatter: 4 independent edges per thread ----------
        int ebase = blockIdx.x * 1024 + threadIdx.x;
        int dd[4], ss[4];
        bool val[4];
        #pragma unroll
        for (int i = 0; i < 4; ++i) {
            int e = ebase + i * 256;
            val[i] = e < E;
            dd[i] = val[i] ? eidx[e] : 0;
            ss[i] = val[i] ? eidx[E + e] : 0;
        }
        int pos[4], o0[4], o1[4];
        #pragma unroll
        for (int i = 0; i < 4; ++i) {
            if (val[i]) {
                pos[i] = atomicAdd(&cur[dd[i]], 1);
                o0[i]  = off[dd[i]];
                o1[i]  = off[dd[i] + 1];
            }
        }
        #pragma unroll
        for (int i = 0; i < 4; ++i) {
            if (!val[i]) continue;
            int e = ebase + i * 256;
            int gbeg_w = pos[i] & ~63;
            int gend_w = min(gbeg_w + 64, E);
            unsigned fl = (unsigned)dd[i];
            if (o0[i] < gbeg_w) fl |= 1u << 30;
            if (o1[i] > gend_w) fl |= 1u << 31;
            rec[pos[i]] = make_int4(e, ss[i], (int)fl, 0);
        }
    } else {
        // ---------- node (2 nodes per block) ----------
        int bb = blockIdx.x - nScat;
        int h = threadIdx.x >> 7;
        int n = bb * 2 + h;
        int t = threadIdx.x & 127;
        if (n < N) {
            x[h][t] = nf[(size_t)n * 128 + t];
            if (t < 16) {
                if (attrs[(size_t)n * 16 + t] > 0.5f) vs[h] = t;   // one-hot
            }
        }
        __syncthreads();
        if (n >= N) return;
        int v = vs[h];
        if (t < 32) {
            int w = t;
            float a = 0.f, b = 0.f;
            #pragma unroll
            for (int u = 0; u < 32; ++u) {
                float xv = x[h][u];
                a = fmaf(xv, l1w0[u * 32 + w], a);
                b = fmaf(xv, scw0[u * 512 + v * 32 + w], b);
            }
            h4[(size_t)n * 128 + w * 4] = a * H_SCALE;
            out[(size_t)n * 128 + w]    = b * FAN_SC;
        } else {
            int j = t - 32;                // 0..95
            int vch = j / 3, m = j - vch * 3;
            float a = 0.f, b = 0.f;
            #pragma unroll
            for (int u = 0; u < 32; ++u) {
                float xv = x[h][32 + u * 3 + m];
                a = fmaf(xv, l1w1[u * 32 + vch], a);
                b = fmaf(xv, scw1[u * 512 + v * 32 + vch], b);
            }
            h4[(size_t)n * 128 + vch * 4 + 1 + m]   = a * H_SCALE;
            out[(size_t)n * 128 + 32 + vch * 3 + m] = b * FAN_SC;
        }
    }
}

// ---------------- legacy scatter (fallback path, small ws) ----------------
__global__ __launch_bounds__(256) void scatter_small(const int* __restrict__ eidx,
                                                     int* __restrict__ cur,
                                                     int4* __restrict__ esd, int E) {
    int e = blockIdx.x * 256 + threadIdx.x;
    if (e >= E) return;
    int d = eidx[e];
    int pos = atomicAdd(&cur[d], 1);
    esd[pos] = make_int4(e, eidx[E + e], d, 0);
}

// ---------------- node stage (fallback path) ----------------
__global__ __launch_bounds__(256) void node_kernel(
    const float* __restrict__ nf, const float* __restrict__ attrs,
    const float* __restrict__ l1w0, const float* __restrict__ l1w1,
    const float* __restrict__ scw0, const float* __restrict__ scw1,
    float* __restrict__ h4, float* __restrict__ out, int N) {
    int h = threadIdx.x >> 7;
    int n = blockIdx.x * 2 + h;
    int t = threadIdx.x & 127;
    __shared__ float x[2][128];
    __shared__ int vs[2];
    if (n < N) {
        x[h][t] = nf[(size_t)n * 128 + t];
        if (t < 16) {
            if (attrs[(size_t)n * 16 + t] > 0.5f) vs[h] = t;
        }
    }
    __syncthreads();
    if (n >= N) return;
    int v = vs[h];
    if (t < 32) {
        int w = t;
        float a = 0.f, b = 0.f;
        #pragma unroll
        for (int u = 0; u < 32; ++u) {
            float xv = x[h][u];
            a = fmaf(xv, l1w0[u * 32 + w], a);
            b = fmaf(xv, scw0[u * 512 + v * 32 + w], b);
        }
        h4[(size_t)n * 128 + w * 4] = a * H_SCALE;
        out[(size_t)n * 128 + w]    = b * FAN_SC;
    } else {
        int j = t - 32;
        int vch = j / 3, m = j - vch * 3;
        float a = 0.f, b = 0.f;
        #pragma unroll
        for (int u = 0; u < 32; ++u) {
            float xv = x[h][32 + u * 3 + m];
            a = fmaf(xv, l1w1[u * 32 + vch], a);
            b = fmaf(xv, scw1[u * 512 + v * 32 + vch], b);
        }
        h4[(size_t)n * 128 + vch * 4 + 1 + m]   = a * H_SCALE;
        out[(size_t)n * 128 + 32 + vch * 3 + m] = b * FAN_SC;
    }
}

// ---------------- FUSED edge kernel: layer1 VALU + layer2 MFMA + window reduce ----
// Startup: 16-B seq record + ONE 64-B einfo line gather (L3-resident).
// FLUSH writes one float4 per lane -> full-line 1-KB bursts (lane-major layout).
__global__ __launch_bounds__(256) void fused_kernel(
    const int4* __restrict__ rec, const uint4* __restrict__ einfo,
    const uint4* __restrict__ wf, const float* __restrict__ w0,
    const float4* __restrict__ h4, float* __restrict__ mn,
    float* __restrict__ sb, int len) {
    __shared__ unsigned amat[256 * 32];        // 32 KB: [edge][64 bf16], XOR-swizzled
    __shared__ unsigned wlds[4][16][66];       // 16.5 KB: per-wave 16-edge pass buffer
    int tid  = threadIdx.x;
    int t    = tid & 63, wid = tid >> 6;
    int m = t & 15, q = t >> 4;
    int gidx = blockIdx.x * 256 + tid;
    bool valid = gidx < len;
    int c = t & 31, half = t >> 5;
    int kk = half ? c + 32 : c;

    // ---- per-edge metadata: one sequential 16-B read + one 64-B einfo line
    int src_t = 0;
    unsigned dstw_t = 0;
    float4 eat = make_float4(0.f, 0.f, 0.f, 0.f);
    float eev[8] = {0.f,0.f,0.f,0.f,0.f,0.f,0.f,0.f};
    if (valid) {
        int4 ev = rec[gidx];
        src_t  = ev.y;
        dstw_t = (unsigned)ev.z;
        const uint4* r = einfo + (size_t)ev.x * 4;
        uint4 ra = r[0], rb = r[1], rc = r[2];
        eev[0] = __uint_as_float(ra.x); eev[1] = __uint_as_float(ra.y);
        eev[2] = __uint_as_float(ra.z); eev[3] = __uint_as_float(ra.w);
        eev[4] = __uint_as_float(rb.x); eev[5] = __uint_as_float(rb.y);
        eev[6] = __uint_as_float(rb.z); eev[7] = __uint_as_float(rb.w);
        eat.x = __uint_as_float(rc.x); eat.y = __uint_as_float(rc.y);
        eat.z = __uint_as_float(rc.z); eat.w = __uint_as_float(rc.w);
    }

    // ---- h4 prefetch slots (rolling, depth 8)
    float4 xs0, xs1, xs2, xs3, xs4, xs5, xs6, xs7;
#define ISSUE_XS(slot, jl) do {                                         \
        int _s = __builtin_amdgcn_readlane(src_t, (jl));                \
        xs##slot = h4[(size_t)_s * 32 + c];                             \
    } while (0)
    ISSUE_XS(0, 0); ISSUE_XS(1, 1); ISSUE_XS(2, 2); ISSUE_XS(3, 3);
    ISSUE_XS(4, 4); ISSUE_XS(5, 5); ISSUE_XS(6, 6); ISSUE_XS(7, 7);

    // ---- B fragments: 16 coalesced b128 loads from precomputed table
    short8 bfL0[4], bfL1[4], bfH0[4], bfH1[4];
    #pragma unroll
    for (int s = 0; s < 4; ++s) {
        bfL0[s] = *(const short8*)&wf[(s * 4 + 0) * 64 + t];
        bfL1[s] = *(const short8*)&wf[(s * 4 + 1) * 64 + t];
        bfH0[s] = *(const short8*)&wf[(s * 4 + 2) * 64 + t];
        bfH1[s] = *(const short8*)&wf[(s * 4 + 3) * 64 + t];
    }

    // ---- layer 1 + silu in chunks of 8, pack + stage into amat (wave-private)
    {
        char* arow = (char*)(amat + tid * 32);
        #pragma unroll
        for (int kc = 0; kc < 8; ++kc) {
            float h[8];
            #pragma unroll
            for (int jj = 0; jj < 8; ++jj) {
                int j = kc * 8 + jj;
                float a = 0.f;
                #pragma unroll
                for (int k = 0; k < 8; ++k) a = fmaf(eev[k], w0[k * 64 + j], a);
                float s = 1.f / (1.f + __expf(-a));
                h[jj] = a * s * W1_SCALE;
            }
            uint4 v = make_uint4(pack_bf16(h[0], h[1]), pack_bf16(h[2], h[3]),
                                 pack_bf16(h[4], h[5]), pack_bf16(h[6], h[7]));
            if (!valid) v = make_uint4(0u, 0u, 0u, 0u);
            *(uint4*)(arow + ((kc * 16) ^ ((tid & 7) << 4))) = v;
        }
    }
    // NO barrier: amat rows [wid*64, wid*64+64) written & read by wave wid only.

    int gbeg = blockIdx.x * 256 + wid * 64;
    if (gbeg >= len) return;
    int cnt  = min(64, len - gbeg);

    // boundary mask for this window (one ballot); compare dst (mask off flags)
    int dmsk = (int)(dstw_t & 0x00FFFFFFu);
    int nxt = __shfl_down(dmsk, 1);
    bool bnd = (t < cnt) && ((t == cnt - 1) || (dmsk != nxt));
    unsigned long long bmask = __ballot(bnd);
    int gwin = gbeg >> 6;

    float acc0 = 0.f, acc1 = 0.f, acc2 = 0.f, acc3 = 0.f;
    unsigned wu0 = 0, wu1 = 0, wu2 = 0, wu3 = 0;

#define MFMA_PASS(p) do {                                                     \
        int row = wid * 64 + (p) * 16 + m;                                    \
        const char* abase = (const char*)(amat + row * 32);                   \
        int swz = (row & 7) << 4;                                             \
        short8 a0 = *(const short8*)(abase + ((q * 16) ^ swz));               \
        short8 a1 = *(const short8*)(abase + ((64 + q * 16) ^ swz));          \
        _Pragma("unroll")                                                     \
        for (int s = 0; s < 4; ++s) {                                         \
            f32x4 dlo = {0.f,0.f,0.f,0.f}, dhi = {0.f,0.f,0.f,0.f};           \
            dlo = __builtin_amdgcn_mfma_f32_16x16x32_bf16(a0, bfL0[s], dlo, 0, 0, 0); \
            dlo = __builtin_amdgcn_mfma_f32_16x16x32_bf16(a1, bfL1[s], dlo, 0, 0, 0); \
            dhi = __builtin_amdgcn_mfma_f32_16x16x32_bf16(a0, bfH0[s], dhi, 0, 0, 0); \
            dhi = __builtin_amdgcn_mfma_f32_16x16x32_bf16(a1, bfH1[s], dhi, 0, 0, 0); \
            _Pragma("unroll")                                                 \
            for (int i = 0; i < 4; ++i)                                       \
                wlds[wid][4 * q + i][s * 16 + m] = pack_bf16(dlo[i], dhi[i]); \
        }                                                                     \
    } while (0)

#define LOADWU(slot, jl) do { wu##slot = wlds[wid][(jl) & 15][kk]; } while (0)

// FLUSH: lane t writes its 4 accs as ONE float4 at row4[t] (lane-major layout)
#define FLUSH(jl) do {                                                 \
        unsigned _w = (unsigned)__builtin_amdgcn_readlane((int)dstw_t, (jl)); \
        int _n = (int)(_w & 0x00FFFFFFu);                               \
        bool _cs = (_w >> 30) & 1u;                                     \
        bool _ce = (_w >> 31) & 1u;                                     \
        float* _dp = (!_cs && !_ce) ? (mn + (size_t)_n * 256)           \
                   : (sb + ((size_t)gwin * 2 + (_cs ? 0 : 1)) * 256);   \
        ((float4*)_dp)[t] = make_float4(acc0, acc1, acc2, acc3);        \
        acc0 = acc1 = acc2 = acc3 = 0.f;                                \
    } while (0)

#define STEP(jl, xss, wus) do {                                         \
        float wlo = bf_lo(wu##wus), whi = bf_hi(wu##wus);               \
        float4 _xs = xs##xss;                                           \
        float _y0  = rl_f(eat.x, (jl));                                 \
        float _y1x = rl_f(eat.y, (jl));                                 \
        float _y1y = rl_f(eat.z, (jl));                                 \
        float _y1z = rl_f(eat.w, (jl));                                 \
        if (half == 0) {                                                \
            acc0 = fmaf(wlo * _xs.x, _y0, acc0);         /* m0a */      \
            float cy = whi * _y0;                                       \
            acc1 = fmaf(cy, _xs.y, acc1);                /* m1b */      \
            acc2 = fmaf(cy, _xs.z, acc2);                               \
            acc3 = fmaf(cy, _xs.w, acc3);                               \
        } else {                                                        \
            float bx = wlo * _xs.x;                                     \
            acc1 = fmaf(bx, _y1x, acc1);                 /* m1a */      \
            acc2 = fmaf(bx, _y1y, acc2);                                \
            acc3 = fmaf(bx, _y1z, acc3);                                \
            float dv = _xs.y * _y1x + _xs.z * _y1y + _xs.w * _y1z;      \
            acc0 = fmaf(whi * SQ3_INVF, dv, acc0);       /* m0b */      \
        }                                                               \
        if ((bmask >> (jl)) & 1) FLUSH(jl);                             \
        if ((jl) + 8 < 64) ISSUE_XS(xss, (jl) + 8);                     \
        if (((jl) & 15) < 12) LOADWU(wus, (jl) + 4);                    \
    } while (0)

#define DO_PASS(p)                                                      \
        MFMA_PASS(p);                                                   \
        LOADWU(0,(p)*16+0); LOADWU(1,(p)*16+1);                         \
        LOADWU(2,(p)*16+2); LOADWU(3,(p)*16+3);                         \
        STEP((p)*16+ 0,0,0); STEP((p)*16+ 1,1,1);                       \
        STEP((p)*16+ 2,2,2); STEP((p)*16+ 3,3,3);                       \
        STEP((p)*16+ 4,4,0); STEP((p)*16+ 5,5,1);                       \
        STEP((p)*16+ 6,6,2); STEP((p)*16+ 7,7,3);                       \
        STEP((p)*16+ 8,0,0); STEP((p)*16+ 9,1,1);                       \
        STEP((p)*16+10,2,2); STEP((p)*16+11,3,3);                       \
        STEP((p)*16+12,4,0); STEP((p)*16+13,5,1);                       \
        STEP((p)*16+14,6,2); STEP((p)*16+15,7,3);

    if (cnt == 64) {
        DO_PASS(0)
        DO_PASS(1)
        DO_PASS(2)
        DO_PASS(3)
    } else {
        // -------- generic short-window path (rare; E%64==0 -> normally unused)
        for (int p = 0; p * 16 < cnt; ++p) {
            MFMA_PASS(p);
            int jbeg = p * 16, jend = min(cnt, p * 16 + 16);
            for (int j = jbeg; j < jend; ++j) {
                unsigned wuv = wlds[wid][j & 15][kk];
                int _s = __builtin_amdgcn_readlane(src_t, j);
                float4 _xs = h4[(size_t)_s * 32 + c];
                float wlo = bf_lo(wuv), whi = bf_hi(wuv);
                float _y0  = rl_f(eat.x, j);
                float _y1x = rl_f(eat.y, j);
                float _y1y = rl_f(eat.z, j);
                float _y1z = rl_f(eat.w, j);
                if (half == 0) {
                    acc0 = fmaf(wlo * _xs.x, _y0, acc0);
                    float cy = whi * _y0;
                    acc1 = fmaf(cy, _xs.y, acc1);
                    acc2 = fmaf(cy, _xs.z, acc2);
                    acc3 = fmaf(cy, _xs.w, acc3);
                } else {
                    float bx = wlo * _xs.x;
                    acc1 = fmaf(bx, _y1x, acc1);
                    acc2 = fmaf(bx, _y1y, acc2);
                    acc3 = fmaf(bx, _y1z, acc3);
                    float dv = _xs.y * _y1x + _xs.z * _y1y + _xs.w * _y1z;
                    acc0 = fmaf(whi * SQ3_INVF, dv, acc0);
                }
                if ((bmask >> j) & 1) FLUSH(j);
            }
        }
    }
#undef DO_PASS
#undef STEP
#undef FLUSH
#undef LOADWU
#undef MFMA_PASS
#undef ISSUE_XS
}

// ---------------- fixup + lin2 (lane-major float4 mn/sb layout) ----------------
__global__ __launch_bounds__(256) void fixlin_kernel(
    const float* __restrict__ mn, const float* __restrict__ sb,
    const int* __restrict__ off,
    const float* __restrict__ l2w0, const float* __restrict__ l2w1,
    float* __restrict__ out, int N) {
    int w = threadIdx.x >> 6, t = threadIdx.x & 63;
    int n = blockIdx.x * 4 + w;
    __shared__ float ld[4][256];
    int c = t & 31, half = t >> 5;
    bool has = false;
    if (n < N) {
        int b = off[n], e = off[n + 1];
        if (e > b) {
            has = true;
            int w0i = b >> 6, w1i = (e - 1) >> 6;
            float4 v;
            if (w0i == w1i) {
                v = ((const float4*)(mn + (size_t)n * 256))[t];   // interior row
            } else {
                v = ((const float4*)(sb + ((size_t)w0i * 2 + 1) * 256))[t];
                for (int ww = w0i + 1; ww <= w1i; ++ww) {
                    float4 qv = ((const float4*)(sb + ((size_t)ww * 2) * 256))[t];
                    v.x += qv.x; v.y += qv.y; v.z += qv.z; v.w += qv.w;
                }
            }
            int p0 = half ? 32 + c : c;
            int p1 = half ? 64 + 3 * c : 160 + 3 * c;
            ld[w][p0] = v.x;
            ld[w][p1] = v.y; ld[w][p1 + 1] = v.z; ld[w][p1 + 2] = v.w;
        }
    }
    __syncthreads();
    if (n < N && has) {
        #pragma unroll
        for (int hh = 0; hh < 2; ++hh) {
            int j = t + hh * 64;
            float acc = 0.f;
            if (j < 32) {
                #pragma unroll
                for (int u = 0; u < 64; ++u) acc = fmaf(ld[w][u], l2w0[u * 32 + j], acc);
            } else {
                int jj = j - 32, vch = jj / 3, m = jj - vch * 3;
                #pragma unroll
                for (int u = 0; u < 64; ++u) acc = fmaf(ld[w][64 + u * 3 + m], l2w1[u * 32 + vch], acc);
            }
            out[(size_t)n * 128 + j] += acc * LIN2_SCALE;
        }
    }
}

// ---------------- FALLBACK (ws too small): round-2 fused gather ----------------
__global__ __launch_bounds__(64) void gather_kernel(
    const float* __restrict__ ee, const float4* __restrict__ eattr4,
    const int4* __restrict__ esd, const int* __restrict__ off,
    const float* __restrict__ w0, const float2* __restrict__ w1p2,
    const float4* __restrict__ h4,
    const float* __restrict__ l2w0, const float* __restrict__ l2w1,
    float* __restrict__ out) {
    int n = blockIdx.x, t = threadIdx.x;
    int beg = off[n], end = off[n + 1];
    __shared__ float s_ee[8];
    __shared__ float s_hid[64];
    __shared__ float ld[256];
    float acc0 = 0.f, acc1 = 0.f, acc2 = 0.f, acc3 = 0.f;
    int c = t & 31;
    for (int i = beg; i < end; ++i) {
        int4 ev = esd[i];
        int e = ev.x, src = ev.y;
        if (t < 8) s_ee[t] = ee[(size_t)e * 8 + t] * SQRT8_INV;
        __syncthreads();
        float a = 0.f;
        #pragma unroll
        for (int k = 0; k < 8; ++k) a = fmaf(s_ee[k], w0[k * 64 + t], a);
        float sg = 1.f / (1.f + __expf(-a));
        __syncthreads();
        s_hid[t] = a * sg * W1_SCALE;
        __syncthreads();
        float wA = 0.f, wB = 0.f;
        #pragma unroll
        for (int j = 0; j < 64; ++j) {
            float2 wv = w1p2[j * 64 + t];
            float hj = s_hid[j];
            wA = fmaf(hj, wv.x, wA);
            wB = fmaf(hj, wv.y, wB);
        }
        float4 xs = h4[(size_t)src * 32 + c];
        float4 ea = eattr4[e];
        if (t < 32) {
            acc0 = fmaf(wA * xs.x, ea.x, acc0);
            float bx = wB * xs.x;
            acc1 = fmaf(bx, ea.y, acc1);
            acc2 = fmaf(bx, ea.z, acc2);
            acc3 = fmaf(bx, ea.w, acc3);
        } else {
            float dv = xs.y * ea.y + xs.z * ea.z + xs.w * ea.w;
            acc0 = fmaf(wB * SQ3_INVF, dv, acc0);
            float cy = wA * ea.x;
            acc1 = fmaf(cy, xs.y, acc1);
            acc2 = fmaf(cy, xs.z, acc2);
            acc3 = fmaf(cy, xs.w, acc3);
        }
    }
    if (t < 32) {
        ld[t] = acc0;
        ld[64 + t * 3 + 0] = acc1;
        ld[64 + t * 3 + 1] = acc2;
        ld[64 + t * 3 + 2] = acc3;
    } else {
        int cc = t - 32;
        ld[32 + cc] = acc0;
        ld[160 + cc * 3 + 0] = acc1;
        ld[160 + cc * 3 + 1] = acc2;
        ld[160 + cc * 3 + 2] = acc3;
    }
    __syncthreads();
    #pragma unroll
    for (int hh = 0; hh < 2; ++hh) {
        int j = t + hh * 64;
        float acc = 0.f;
        if (j < 32) {
            #pragma unroll
            for (int u = 0; u < 64; ++u) acc = fmaf(ld[u], l2w0[u * 32 + j], acc);
        } else {
            int jj = j - 32, vch = jj / 3, m = jj - vch * 3;
            #pragma unroll
            for (int u = 0; u < 64; ++u) acc = fmaf(ld[64 + u * 3 + m], l2w1[u * 32 + vch], acc);
        }
        out[(size_t)n * 128 + j] += acc * LIN2_SCALE;
    }
}

extern "C" void kernel_launch(void* const* d_in, const int* in_sizes, int n_in,
                              void* d_out, int out_size, void* d_ws, size_t ws_size,
                              hipStream_t stream) {
    const float* nf    = (const float*)d_in[0];
    const float* attrs = (const float*)d_in[1];
    const float* eattr = (const float*)d_in[2];
    const float* ee    = (const float*)d_in[3];
    const int*   eidx  = (const int*)d_in[4];
    const float* l1w0  = (const float*)d_in[5];
    const float* l1w1  = (const float*)d_in[6];
    const float* w0    = (const float*)d_in[7];
    const float* w1    = (const float*)d_in[8];
    const float* l2w0  = (const float*)d_in[9];
    const float* l2w1  = (const float*)d_in[10];
    const float* scw0  = (const float*)d_in[11];
    const float* scw1  = (const float*)d_in[12];

    int N = in_sizes[0] / 128;
    int E = in_sizes[3] / 8;
    int nb = (N + 255) / 256;
    int nw = (E + 63) / 64;

    // ws layout: h4 | wf | w1p | cnt | off | cur | bsum | rec(16B) | einfo(64B) | mn | sb
    float* h4    = (float*)d_ws;                       // N*128
    float* wfp   = h4 + (size_t)N * 128;               // 4096 floats (16 KB)
    float* w1p   = wfp + 4096;                         // 8192
    int*   cnt   = (int*)(w1p + 8192);                 // N
    int*   off   = cnt + N;                            // N+1
    int*   cur   = off + N + 1;                        // N
    int*   bsum  = cur + N;                            // nb
    size_t rec_off = (((size_t)((char*)(bsum + nb) - (char*)d_ws)) + 63) & ~(size_t)63;
    int4*  rec   = (int4*)((char*)d_ws + rec_off);     // E int4 (16 B/edge)
    uint4* einfo = (uint4*)(rec + (size_t)E);          // E*4 uint4 (64 B/edge)
    float* mn    = (float*)(einfo + (size_t)E * 4);    // N*256
    float* sb    = mn + (size_t)N * 256;               // nw*512
    size_t need  = (size_t)((char*)(sb + (size_t)nw * 512) - (char*)d_ws);
    bool big = ws_size >= need;

    hipMemsetAsync(cnt, 0, (size_t)N * sizeof(int), stream);

    if (big) {
        int nH = (E / 4 + 256) / 256;
        int nP = (E + 255) / 256;
        histprep_kernel<<<nH + nP, 256, 0, stream>>>(eidx, cnt, (const float4*)ee,
                                                     (const float4*)eattr, einfo, E, nH);
        scan_bsum<<<nb, 256, 0, stream>>>(cnt, bsum, N);
        bscan_prep<<<5, 1024, 0, stream>>>(bsum, nb, w1, (uint4*)wfp);
        scan_final<<<nb, 256, 0, stream>>>(cnt, bsum, off, cur, N);
        int nScat = (E + 1023) / 1024;
        int nNode = (N + 1) / 2;
        scatnode_kernel<<<nScat + nNode, 256, 0, stream>>>(
            eidx, cur, off, rec, E, nScat,
            nf, attrs, l1w0, l1w1, scw0, scw1, h4, (float*)d_out, N);
        fused_kernel<<<(E + 255) / 256, 256, 0, stream>>>(rec, einfo,
                                                          (const uint4*)wfp, w0,
                                                          (const float4*)h4,
                                                          mn, sb, E);
        fixlin_kernel<<<(N + 3) / 4, 256, 0, stream>>>(mn, sb, off, l2w0, l2w1,
                                                       (float*)d_out, N);
    } else {
        int nH = (E / 4 + 256) / 256;
        histprep_kernel<<<nH, 256, 0, stream>>>(eidx, cnt, (const float4*)ee,
                                                (const float4*)eattr, (uint4*)rec, E, nH);
        scan_bsum<<<nb, 256, 0, stream>>>(cnt, bsum, N);
        bscan_prep<<<5, 1024, 0, stream>>>(bsum, nb, w1, (uint4*)wfp);
        scan_final<<<nb, 256, 0, stream>>>(cnt, bsum, off, cur, N);
        prep_w1p<<<16, 256, 0, stream>>>(w1, w1p);
        scatter_small<<<(E + 255) / 256, 256, 0, stream>>>(eidx, cur, rec, E);
        node_kernel<<<(N + 1) / 2, 256, 0, stream>>>(nf, attrs, l1w0, l1w1, scw0, scw1,
                                                     h4, (float*)d_out, N);
        gather_kernel<<<N, 64, 0, stream>>>(ee, (const float4*)eattr, rec,
                                            off, w0, (const float2*)w1p,
                                            (const float4*)h4,
                                            l2w0, l2w1, (float*)d_out);
    }
}

// Round 18
// 264.560 us; speedup vs baseline: 1.1182x; 1.1182x over previous
//
#include <hip/hip_runtime.h>
#include <math.h>

#define SQRT8_INV  0.35355339059327373f   // 1/sqrt(8)
#define H_SCALE    0.04419417382415922f   // 0.25/sqrt(32)
#define FAN_SC     0.04419417382415922f   // 1/sqrt(32*16)
#define W1_SCALE   0.125f                 // 1/sqrt(64)
#define LIN2_SCALE 0.125f                 // 1/sqrt(64)
#define SQ3_INVF   0.57735026918962576f   // 1/sqrt(3)

typedef __attribute__((ext_vector_type(8))) short short8;
typedef __attribute__((ext_vector_type(4))) float f32x4;

__device__ __forceinline__ unsigned pack_bf16(float a, float b) {
    unsigned ua = __float_as_uint(a);
    ua += 0x7FFFu + ((ua >> 16) & 1u);          // RNE
    unsigned ub = __float_as_uint(b);
    ub += 0x7FFFu + ((ub >> 16) & 1u);
    return (ua >> 16) | (ub & 0xFFFF0000u);
}
__device__ __forceinline__ float bf_lo(unsigned u) { return __uint_as_float(u << 16); }
__device__ __forceinline__ float bf_hi(unsigned u) { return __uint_as_float(u & 0xFFFF0000u); }
__device__ __forceinline__ float rl_f(float v, int l) {
    return __uint_as_float(__builtin_amdgcn_readlane(__float_as_uint(v), l));
}

// ---------------- w1 -> w1p (fallback gather path) ----------------
__global__ __launch_bounds__(256) void prep_w1p(const float* __restrict__ w1,
                                                float* __restrict__ w1p) {
    int idx = blockIdx.x * 256 + threadIdx.x;
    if (idx >= 64 * 64) return;
    int j = idx >> 6, t = idx & 63;
    int colA = (t < 32) ? t : t + 32;
    int colB = (t < 32) ? t + 32 : t + 64;
    w1p[idx * 2 + 0] = w1[j * 128 + colA];
    w1p[idx * 2 + 1] = w1[j * 128 + colB];
}

// ---------------- histogram of edge_dst; RETURNING atomic -> rank[e] ----------------
__global__ __launch_bounds__(256) void hist_kernel(const int* __restrict__ eidx,
                                                   int* __restrict__ cnt,
                                                   int* __restrict__ rank, int E) {
    int i = blockIdx.x * 256 + threadIdx.x;
    int base = i * 4;
    if (base + 3 < E) {
        int4 v = ((const int4*)eidx)[i];
        int r0 = atomicAdd(&cnt[v.x], 1);
        int r1 = atomicAdd(&cnt[v.y], 1);
        int r2 = atomicAdd(&cnt[v.z], 1);
        int r3 = atomicAdd(&cnt[v.w], 1);
        ((int4*)rank)[i] = make_int4(r0, r1, r2, r3);
    } else {
        for (int e = base; e < E; ++e) rank[e] = atomicAdd(&cnt[eidx[e]], 1);
    }
}

// ---------------- hierarchical scan, stage A: per-block sums ----------------
__global__ __launch_bounds__(256) void scan_bsum(const int* __restrict__ cnt,
                                                 int* __restrict__ bsum, int N) {
    __shared__ int red[256];
    int t = threadIdx.x, i = blockIdx.x * 256 + t;
    red[t] = (i < N) ? cnt[i] : 0;
    __syncthreads();
    #pragma unroll
    for (int d = 128; d > 0; d >>= 1) {
        if (t < d) red[t] += red[t + d];
        __syncthreads();
    }
    if (t == 0) bsum[blockIdx.x] = red[0];
}

// ---------------- stage B (block 0) + prep_wf (blocks 1..4) ----------------
__global__ __launch_bounds__(1024) void bscan_prep(int* __restrict__ bsum, int nb,
                                                   const float* __restrict__ w1,
                                                   uint4* __restrict__ wf) {
    if (blockIdx.x == 0) {
        __shared__ int s[1024];
        int t = threadIdx.x;
        int v = (t < nb) ? bsum[t] : 0;
        s[t] = v;
        __syncthreads();
        for (int d = 1; d < 1024; d <<= 1) {
            int u = (t >= d) ? s[t - d] : 0;
            __syncthreads();
            s[t] += u;
            __syncthreads();
        }
        if (t < nb) bsum[t] = s[t] - v;   // exclusive
    } else if (threadIdx.x < 256) {
        int idx = (blockIdx.x - 1) * 256 + threadIdx.x;   // 0..1023
        int lane = idx & 63, part = (idx >> 6) & 3, sq = idx >> 8;
        int m = lane & 15, q = lane >> 4;
        int col = sq * 16 + m + ((part & 2) ? 64 : 0);
        int kb  = (part & 1) ? 32 : 0;
        unsigned u[4];
        #pragma unroll
        for (int i2 = 0; i2 < 4; ++i2) {
            float a = w1[(kb + q * 8 + i2 * 2 + 0) * 128 + col];
            float b = w1[(kb + q * 8 + i2 * 2 + 1) * 128 + col];
            unsigned ua = __float_as_uint(a); ua += 0x7FFFu + ((ua >> 16) & 1u);
            unsigned ub = __float_as_uint(b); ub += 0x7FFFu + ((ub >> 16) & 1u);
            u[i2] = (ua >> 16) | (ub & 0xFFFF0000u);
        }
        wf[idx] = make_uint4(u[0], u[1], u[2], u[3]);
    }
}

// ---------------- stage C: in-block scan + base -> off, cur ----------------
__global__ __launch_bounds__(256) void scan_final(const int* __restrict__ cnt,
                                                  const int* __restrict__ bsum,
                                                  int* __restrict__ off,
                                                  int* __restrict__ cur, int N) {
    __shared__ int s[256];
    int t = threadIdx.x, i = blockIdx.x * 256 + t;
    int v = (i < N) ? cnt[i] : 0;
    s[t] = v;
    __syncthreads();
    for (int d = 1; d < 256; d <<= 1) {
        int u = (t >= d) ? s[t - d] : 0;
        __syncthreads();
        s[t] += u;
        __syncthreads();
    }
    int ex = s[t] - v + bsum[blockIdx.x];
    if (i < N) { off[i] = ex; cur[i] = ex; }
    if (i == N - 1) off[N] = ex + v;
}

// ---------------- MERGED atomic-free scatter (fat 64-B record) + node ----------
// pos = off[d] + rank[e] (bijective per segment). No atomics.
// rec[pos] (4 x uint4): [0]=ee[0..3]*s8  [1]=ee[4..7]*s8  [2]=eattr
//                        [3]={src, dst | cs<<30 | ce<<31, 0, 0}
__global__ __launch_bounds__(256) void scatnode_kernel(
    const int* __restrict__ eidx, const int* __restrict__ rank,
    const float4* __restrict__ ee2, const float4* __restrict__ eattr4,
    const int* __restrict__ off, uint4* __restrict__ rec, int E, int nScat,
    const float* __restrict__ nf, const float* __restrict__ attrs,
    const float* __restrict__ l1w0, const float* __restrict__ l1w1,
    const float* __restrict__ scw0, const float* __restrict__ scw1,
    float* __restrict__ h4, float* __restrict__ out, int N) {
    __shared__ float x[2][128];
    __shared__ int vs[2];
    if (blockIdx.x < nScat) {
        // ---------- scatter: NO atomics, pos from rank ----------
        int e = blockIdx.x * 256 + threadIdx.x;
        if (e >= E) return;
        int d   = eidx[e];
        int src = eidx[E + e];
        int r   = rank[e];
        int o0  = off[d], o1 = off[d + 1];
        int pos = o0 + r;
        int gbeg_w = pos & ~63;
        int gend_w = min(gbeg_w + 64, E);
        unsigned fl = (unsigned)d;
        if (o0 < gbeg_w) fl |= 1u << 30;
        if (o1 > gend_w) fl |= 1u << 31;
        float4 e0 = ee2[(size_t)e * 2], e1 = ee2[(size_t)e * 2 + 1];
        float4 ea = eattr4[e];
        e0.x *= SQRT8_INV; e0.y *= SQRT8_INV; e0.z *= SQRT8_INV; e0.w *= SQRT8_INV;
        e1.x *= SQRT8_INV; e1.y *= SQRT8_INV; e1.z *= SQRT8_INV; e1.w *= SQRT8_INV;
        uint4* rp = rec + (size_t)pos * 4;
        rp[0] = make_uint4(__float_as_uint(e0.x), __float_as_uint(e0.y),
                           __float_as_uint(e0.z), __float_as_uint(e0.w));
        rp[1] = make_uint4(__float_as_uint(e1.x), __float_as_uint(e1.y),
                           __float_as_uint(e1.z), __float_as_uint(e1.w));
        rp[2] = make_uint4(__float_as_uint(ea.x), __float_as_uint(ea.y),
                           __float_as_uint(ea.z), __float_as_uint(ea.w));
        rp[3] = make_uint4((unsigned)src, fl, 0u, 0u);
    } else {
        // ---------- node (2 nodes per block) ----------
        int bb = blockIdx.x - nScat;
        int h = threadIdx.x >> 7;
        int n = bb * 2 + h;
        int t = threadIdx.x & 127;
        if (n < N) {
            x[h][t] = nf[(size_t)n * 128 + t];
            if (t < 16) {
                if (attrs[(size_t)n * 16 + t] > 0.5f) vs[h] = t;   // one-hot
            }
        }
        __syncthreads();
        if (n >= N) return;
        int v = vs[h];
        if (t < 32) {
            int w = t;
            float a = 0.f, b = 0.f;
            #pragma unroll
            for (int u = 0; u < 32; ++u) {
                float xv = x[h][u];
                a = fmaf(xv, l1w0[u * 32 + w], a);
                b = fmaf(xv, scw0[u * 512 + v * 32 + w], b);
            }
            h4[(size_t)n * 128 + w * 4] = a * H_SCALE;
            out[(size_t)n * 128 + w]    = b * FAN_SC;
        } else {
            int j = t - 32;                // 0..95
            int vch = j / 3, m = j - vch * 3;
            float a = 0.f, b = 0.f;
            #pragma unroll
            for (int u = 0; u < 32; ++u) {
                float xv = x[h][32 + u * 3 + m];
                a = fmaf(xv, l1w1[u * 32 + vch], a);
                b = fmaf(xv, scw1[u * 512 + v * 32 + vch], b);
            }
            h4[(size_t)n * 128 + vch * 4 + 1 + m]   = a * H_SCALE;
            out[(size_t)n * 128 + 32 + vch * 3 + m] = b * FAN_SC;
        }
    }
}

// ---------------- legacy scatter (fallback path, small ws) ----------------
__global__ __launch_bounds__(256) void scatter_small(const int* __restrict__ eidx,
                                                     int* __restrict__ cur,
                                                     int4* __restrict__ esd, int E) {
    int e = blockIdx.x * 256 + threadIdx.x;
    if (e >= E) return;
    int d = eidx[e];
    int pos = atomicAdd(&cur[d], 1);
    esd[pos] = make_int4(e, eidx[E + e], d, 0);
}

// ---------------- node stage (fallback path) ----------------
__global__ __launch_bounds__(256) void node_kernel(
    const float* __restrict__ nf, const float* __restrict__ attrs,
    const float* __restrict__ l1w0, const float* __restrict__ l1w1,
    const float* __restrict__ scw0, const float* __restrict__ scw1,
    float* __restrict__ h4, float* __restrict__ out, int N) {
    int h = threadIdx.x >> 7;
    int n = blockIdx.x * 2 + h;
    int t = threadIdx.x & 127;
    __shared__ float x[2][128];
    __shared__ int vs[2];
    if (n < N) {
        x[h][t] = nf[(size_t)n * 128 + t];
        if (t < 16) {
            if (attrs[(size_t)n * 16 + t] > 0.5f) vs[h] = t;
        }
    }
    __syncthreads();
    if (n >= N) return;
    int v = vs[h];
    if (t < 32) {
        int w = t;
        float a = 0.f, b = 0.f;
        #pragma unroll
        for (int u = 0; u < 32; ++u) {
            float xv = x[h][u];
            a = fmaf(xv, l1w0[u * 32 + w], a);
            b = fmaf(xv, scw0[u * 512 + v * 32 + w], b);
        }
        h4[(size_t)n * 128 + w * 4] = a * H_SCALE;
        out[(size_t)n * 128 + w]    = b * FAN_SC;
    } else {
        int j = t - 32;
        int vch = j / 3, m = j - vch * 3;
        float a = 0.f, b = 0.f;
        #pragma unroll
        for (int u = 0; u < 32; ++u) {
            float xv = x[h][32 + u * 3 + m];
            a = fmaf(xv, l1w1[u * 32 + vch], a);
            b = fmaf(xv, scw1[u * 512 + v * 32 + vch], b);
        }
        h4[(size_t)n * 128 + vch * 4 + 1 + m]   = a * H_SCALE;
        out[(size_t)n * 128 + 32 + vch * 3 + m] = b * FAN_SC;
    }
}

// ---------------- FUSED edge kernel: layer1 VALU + layer2 MFMA + window reduce ----
// Startup: ONE sequential 64-B record read. FLUSH = lane-major float4 (full lines).
__global__ __launch_bounds__(256) void fused_kernel(
    const uint4* __restrict__ rec, const uint4* __restrict__ wf,
    const float* __restrict__ w0,
    const float4* __restrict__ h4, float* __restrict__ mn,
    float* __restrict__ sb, int len) {
    __shared__ unsigned amat[256 * 32];        // 32 KB: [edge][64 bf16], XOR-swizzled
    __shared__ unsigned wlds[4][16][66];       // 16.5 KB: per-wave 16-edge pass buffer
    int tid  = threadIdx.x;
    int t    = tid & 63, wid = tid >> 6;
    int m = t & 15, q = t >> 4;
    int gidx = blockIdx.x * 256 + tid;
    bool valid = gidx < len;
    int c = t & 31, half = t >> 5;
    int kk = half ? c + 32 : c;

    // ---- per-edge metadata: one sequential 64-B read
    float4 eat = make_float4(0.f, 0.f, 0.f, 0.f);
    float eev[8] = {0.f,0.f,0.f,0.f,0.f,0.f,0.f,0.f};
    int src_t = 0;
    unsigned dstw_t = 0;
    if (valid) {
        const uint4* r = rec + (size_t)gidx * 4;
        uint4 ra = r[0], rb = r[1], rc = r[2], rd = r[3];
        eev[0] = __uint_as_float(ra.x); eev[1] = __uint_as_float(ra.y);
        eev[2] = __uint_as_float(ra.z); eev[3] = __uint_as_float(ra.w);
        eev[4] = __uint_as_float(rb.x); eev[5] = __uint_as_float(rb.y);
        eev[6] = __uint_as_float(rb.z); eev[7] = __uint_as_float(rb.w);
        eat.x = __uint_as_float(rc.x); eat.y = __uint_as_float(rc.y);
        eat.z = __uint_as_float(rc.z); eat.w = __uint_as_float(rc.w);
        src_t  = (int)rd.x;
        dstw_t = rd.y;
    }

    // ---- h4 prefetch slots (rolling, depth 8)
    float4 xs0, xs1, xs2, xs3, xs4, xs5, xs6, xs7;
#define ISSUE_XS(slot, jl) do {                                         \
        int _s = __builtin_amdgcn_readlane(src_t, (jl));                \
        xs##slot = h4[(size_t)_s * 32 + c];                             \
    } while (0)
    ISSUE_XS(0, 0); ISSUE_XS(1, 1); ISSUE_XS(2, 2); ISSUE_XS(3, 3);
    ISSUE_XS(4, 4); ISSUE_XS(5, 5); ISSUE_XS(6, 6); ISSUE_XS(7, 7);

    // ---- B fragments: 16 coalesced b128 loads from precomputed table
    short8 bfL0[4], bfL1[4], bfH0[4], bfH1[4];
    #pragma unroll
    for (int s = 0; s < 4; ++s) {
        bfL0[s] = *(const short8*)&wf[(s * 4 + 0) * 64 + t];
        bfL1[s] = *(const short8*)&wf[(s * 4 + 1) * 64 + t];
        bfH0[s] = *(const short8*)&wf[(s * 4 + 2) * 64 + t];
        bfH1[s] = *(const short8*)&wf[(s * 4 + 3) * 64 + t];
    }

    // ---- layer 1 + silu in chunks of 8, pack + stage into amat (wave-private)
    {
        char* arow = (char*)(amat + tid * 32);
        #pragma unroll
        for (int kc = 0; kc < 8; ++kc) {
            float h[8];
            #pragma unroll
            for (int jj = 0; jj < 8; ++jj) {
                int j = kc * 8 + jj;
                float a = 0.f;
                #pragma unroll
                for (int k = 0; k < 8; ++k) a = fmaf(eev[k], w0[k * 64 + j], a);
                float s = 1.f / (1.f + __expf(-a));
                h[jj] = a * s * W1_SCALE;
            }
            uint4 v = make_uint4(pack_bf16(h[0], h[1]), pack_bf16(h[2], h[3]),
                                 pack_bf16(h[4], h[5]), pack_bf16(h[6], h[7]));
            if (!valid) v = make_uint4(0u, 0u, 0u, 0u);
            *(uint4*)(arow + ((kc * 16) ^ ((tid & 7) << 4))) = v;
        }
    }
    // NO barrier: amat rows [wid*64, wid*64+64) written & read by wave wid only.

    int gbeg = blockIdx.x * 256 + wid * 64;
    if (gbeg >= len) return;
    int cnt  = min(64, len - gbeg);

    // boundary mask for this window (one ballot); compare dst (mask off flags)
    int dmsk = (int)(dstw_t & 0x00FFFFFFu);
    int nxt = __shfl_down(dmsk, 1);
    bool bnd = (t < cnt) && ((t == cnt - 1) || (dmsk != nxt));
    unsigned long long bmask = __ballot(bnd);
    int gwin = gbeg >> 6;

    float acc0 = 0.f, acc1 = 0.f, acc2 = 0.f, acc3 = 0.f;
    unsigned wu0 = 0, wu1 = 0, wu2 = 0, wu3 = 0;

#define MFMA_PASS(p) do {                                                     \
        int row = wid * 64 + (p) * 16 + m;                                    \
        const char* abase = (const char*)(amat + row * 32);                   \
        int swz = (row & 7) << 4;                                             \
        short8 a0 = *(const short8*)(abase + ((q * 16) ^ swz));               \
        short8 a1 = *(const short8*)(abase + ((64 + q * 16) ^ swz));          \
        _Pragma("unroll")                                                     \
        for (int s = 0; s < 4; ++s) {                                         \
            f32x4 dlo = {0.f,0.f,0.f,0.f}, dhi = {0.f,0.f,0.f,0.f};           \
            dlo = __builtin_amdgcn_mfma_f32_16x16x32_bf16(a0, bfL0[s], dlo, 0, 0, 0); \
            dlo = __builtin_amdgcn_mfma_f32_16x16x32_bf16(a1, bfL1[s], dlo, 0, 0, 0); \
            dhi = __builtin_amdgcn_mfma_f32_16x16x32_bf16(a0, bfH0[s], dhi, 0, 0, 0); \
            dhi = __builtin_amdgcn_mfma_f32_16x16x32_bf16(a1, bfH1[s], dhi, 0, 0, 0); \
            _Pragma("unroll")                                                 \
            for (int i = 0; i < 4; ++i)                                       \
                wlds[wid][4 * q + i][s * 16 + m] = pack_bf16(dlo[i], dhi[i]); \
        }                                                                     \
    } while (0)

#define LOADWU(slot, jl) do { wu##slot = wlds[wid][(jl) & 15][kk]; } while (0)

// FLUSH: lane t writes its 4 accs as ONE float4 at row4[t] (lane-major layout)
#define FLUSH(jl) do {                                                 \
        unsigned _w = (unsigned)__builtin_amdgcn_readlane((int)dstw_t, (jl)); \
        int _n = (int)(_w & 0x00FFFFFFu);                               \
        bool _cs = (_w >> 30) & 1u;                                     \
        bool _ce = (_w >> 31) & 1u;                                     \
        float* _dp = (!_cs && !_ce) ? (mn + (size_t)_n * 256)           \
                   : (sb + ((size_t)gwin * 2 + (_cs ? 0 : 1)) * 256);   \
        ((float4*)_dp)[t] = make_float4(acc0, acc1, acc2, acc3);        \
        acc0 = acc1 = acc2 = acc3 = 0.f;                                \
    } while (0)

#define STEP(jl, xss, wus) do {                                         \
        float wlo = bf_lo(wu##wus), whi = bf_hi(wu##wus);               \
        float4 _xs = xs##xss;                                           \
        float _y0  = rl_f(eat.x, (jl));                                 \
        float _y1x = rl_f(eat.y, (jl));                                 \
        float _y1y = rl_f(eat.z, (jl));                                 \
        float _y1z = rl_f(eat.w, (jl));                                 \
        if (half == 0) {                                                \
            acc0 = fmaf(wlo * _xs.x, _y0, acc0);         /* m0a */      \
            float cy = whi * _y0;                                       \
            acc1 = fmaf(cy, _xs.y, acc1);                /* m1b */      \
            acc2 = fmaf(cy, _xs.z, acc2);                               \
            acc3 = fmaf(cy, _xs.w, acc3);                               \
        } else {                                                        \
            float bx = wlo * _xs.x;                                     \
            acc1 = fmaf(bx, _y1x, acc1);                 /* m1a */      \
            acc2 = fmaf(bx, _y1y, acc2);                                \
            acc3 = fmaf(bx, _y1z, acc3);                                \
            float dv = _xs.y * _y1x + _xs.z * _y1y + _xs.w * _y1z;      \
            acc0 = fmaf(whi * SQ3_INVF, dv, acc0);       /* m0b */      \
        }                                                               \
        if ((bmask >> (jl)) & 1) FLUSH(jl);                             \
        if ((jl) + 8 < 64) ISSUE_XS(xss, (jl) + 8);                     \
        if (((jl) & 15) < 12) LOADWU(wus, (jl) + 4);                    \
    } while (0)

#define DO_PASS(p)                                                      \
        MFMA_PASS(p);                                                   \
        LOADWU(0,(p)*16+0); LOADWU(1,(p)*16+1);                         \
        LOADWU(2,(p)*16+2); LOADWU(3,(p)*16+3);                         \
        STEP((p)*16+ 0,0,0); STEP((p)*16+ 1,1,1);                       \
        STEP((p)*16+ 2,2,2); STEP((p)*16+ 3,3,3);                       \
        STEP((p)*16+ 4,4,0); STEP((p)*16+ 5,5,1);                       \
        STEP((p)*16+ 6,6,2); STEP((p)*16+ 7,7,3);                       \
        STEP((p)*16+ 8,0,0); STEP((p)*16+ 9,1,1);                       \
        STEP((p)*16+10,2,2); STEP((p)*16+11,3,3);                       \
        STEP((p)*16+12,4,0); STEP((p)*16+13,5,1);                       \
        STEP((p)*16+14,6,2); STEP((p)*16+15,7,3);

    if (cnt == 64) {
        DO_PASS(0)
        DO_PASS(1)
        DO_PASS(2)
        DO_PASS(3)
    } else {
        // -------- generic short-window path (rare; E%64==0 -> normally unused)
        for (int p = 0; p * 16 < cnt; ++p) {
            MFMA_PASS(p);
            int jbeg = p * 16, jend = min(cnt, p * 16 + 16);
            for (int j = jbeg; j < jend; ++j) {
                unsigned wuv = wlds[wid][j & 15][kk];
                int _s = __builtin_amdgcn_readlane(src_t, j);
                float4 _xs = h4[(size_t)_s * 32 + c];
                float wlo = bf_lo(wuv), whi = bf_hi(wuv);
                float _y0  = rl_f(eat.x, j);
                float _y1x = rl_f(eat.y, j);
                float _y1y = rl_f(eat.z, j);
                float _y1z = rl_f(eat.w, j);
                if (half == 0) {
                    acc0 = fmaf(wlo * _xs.x, _y0, acc0);
                    float cy = whi * _y0;
                    acc1 = fmaf(cy, _xs.y, acc1);
                    acc2 = fmaf(cy, _xs.z, acc2);
                    acc3 = fmaf(cy, _xs.w, acc3);
                } else {
                    float bx = wlo * _xs.x;
                    acc1 = fmaf(bx, _y1x, acc1);
                    acc2 = fmaf(bx, _y1y, acc2);
                    acc3 = fmaf(bx, _y1z, acc3);
                    float dv = _xs.y * _y1x + _xs.z * _y1y + _xs.w * _y1z;
                    acc0 = fmaf(whi * SQ3_INVF, dv, acc0);
                }
                if ((bmask >> j) & 1) FLUSH(j);
            }
        }
    }
#undef DO_PASS
#undef STEP
#undef FLUSH
#undef LOADWU
#undef MFMA_PASS
#undef ISSUE_XS
}

// ---------------- fixup + lin2 (lane-major float4 mn/sb layout) ----------------
__global__ __launch_bounds__(256) void fixlin_kernel(
    const float* __restrict__ mn, const float* __restrict__ sb,
    const int* __restrict__ off,
    const float* __restrict__ l2w0, const float* __restrict__ l2w1,
    float* __restrict__ out, int N) {
    int w = threadIdx.x >> 6, t = threadIdx.x & 63;
    int n = blockIdx.x * 4 + w;
    __shared__ float ld[4][256];
    int c = t & 31, half = t >> 5;
    bool has = false;
    if (n < N) {
        int b = off[n], e = off[n + 1];
        if (e > b) {
            has = true;
            int w0i = b >> 6, w1i = (e - 1) >> 6;
            float4 v;
            if (w0i == w1i) {
                v = ((const float4*)(mn + (size_t)n * 256))[t];   // interior row
            } else {
                v = ((const float4*)(sb + ((size_t)w0i * 2 + 1) * 256))[t];
                for (int ww = w0i + 1; ww <= w1i; ++ww) {
                    float4 qv = ((const float4*)(sb + ((size_t)ww * 2) * 256))[t];
                    v.x += qv.x; v.y += qv.y; v.z += qv.z; v.w += qv.w;
                }
            }
            int p0 = half ? 32 + c : c;
            int p1 = half ? 64 + 3 * c : 160 + 3 * c;
            ld[w][p0] = v.x;
            ld[w][p1] = v.y; ld[w][p1 + 1] = v.z; ld[w][p1 + 2] = v.w;
        }
    }
    __syncthreads();
    if (n < N && has) {
        #pragma unroll
        for (int hh = 0; hh < 2; ++hh) {
            int j = t + hh * 64;
            float acc = 0.f;
            if (j < 32) {
                #pragma unroll
                for (int u = 0; u < 64; ++u) acc = fmaf(ld[w][u], l2w0[u * 32 + j], acc);
            } else {
                int jj = j - 32, vch = jj / 3, m = jj - vch * 3;
                #pragma unroll
                for (int u = 0; u < 64; ++u) acc = fmaf(ld[w][64 + u * 3 + m], l2w1[u * 32 + vch], acc);
            }
            out[(size_t)n * 128 + j] += acc * LIN2_SCALE;
        }
    }
}

// ---------------- FALLBACK (ws too small): round-2 fused gather ----------------
__global__ __launch_bounds__(64) void gather_kernel(
    const float* __restrict__ ee, const float4* __restrict__ eattr4,
    const int4* __restrict__ esd, const int* __restrict__ off,
    const float* __restrict__ w0, const float2* __restrict__ w1p2,
    const float4* __restrict__ h4,
    const float* __restrict__ l2w0, const float* __restrict__ l2w1,
    float* __restrict__ out) {
    int n = blockIdx.x, t = threadIdx.x;
    int beg = off[n], end = off[n + 1];
    __shared__ float s_ee[8];
    __shared__ float s_hid[64];
    __shared__ float ld[256];
    float acc0 = 0.f, acc1 = 0.f, acc2 = 0.f, acc3 = 0.f;
    int c = t & 31;
    for (int i = beg; i < end; ++i) {
        int4 ev = esd[i];
        int e = ev.x, src = ev.y;
        if (t < 8) s_ee[t] = ee[(size_t)e * 8 + t] * SQRT8_INV;
        __syncthreads();
        float a = 0.f;
        #pragma unroll
        for (int k = 0; k < 8; ++k) a = fmaf(s_ee[k], w0[k * 64 + t], a);
        float sg = 1.f / (1.f + __expf(-a));
        __syncthreads();
        s_hid[t] = a * sg * W1_SCALE;
        __syncthreads();
        float wA = 0.f, wB = 0.f;
        #pragma unroll
        for (int j = 0; j < 64; ++j) {
            float2 wv = w1p2[j * 64 + t];
            float hj = s_hid[j];
            wA = fmaf(hj, wv.x, wA);
            wB = fmaf(hj, wv.y, wB);
        }
        float4 xs = h4[(size_t)src * 32 + c];
        float4 ea = eattr4[e];
        if (t < 32) {
            acc0 = fmaf(wA * xs.x, ea.x, acc0);
            float bx = wB * xs.x;
            acc1 = fmaf(bx, ea.y, acc1);
            acc2 = fmaf(bx, ea.z, acc2);
            acc3 = fmaf(bx, ea.w, acc3);
        } else {
            float dv = xs.y * ea.y + xs.z * ea.z + xs.w * ea.w;
            acc0 = fmaf(wB * SQ3_INVF, dv, acc0);
            float cy = wA * ea.x;
            acc1 = fmaf(cy, xs.y, acc1);
            acc2 = fmaf(cy, xs.z, acc2);
            acc3 = fmaf(cy, xs.w, acc3);
        }
    }
    if (t < 32) {
        ld[t] = acc0;
        ld[64 + t * 3 + 0] = acc1;
        ld[64 + t * 3 + 1] = acc2;
        ld[64 + t * 3 + 2] = acc3;
    } else {
        int cc = t - 32;
        ld[32 + cc] = acc0;
        ld[160 + cc * 3 + 0] = acc1;
        ld[160 + cc * 3 + 1] = acc2;
        ld[160 + cc * 3 + 2] = acc3;
    }
    __syncthreads();
    #pragma unroll
    for (int hh = 0; hh < 2; ++hh) {
        int j = t + hh * 64;
        float acc = 0.f;
        if (j < 32) {
            #pragma unroll
            for (int u = 0; u < 64; ++u) acc = fmaf(ld[u], l2w0[u * 32 + j], acc);
        } else {
            int jj = j - 32, vch = jj / 3, m = jj - vch * 3;
            #pragma unroll
            for (int u = 0; u < 64; ++u) acc = fmaf(ld[64 + u * 3 + m], l2w1[u * 32 + vch], acc);
        }
        out[(size_t)n * 128 + j] += acc * LIN2_SCALE;
    }
}

extern "C" void kernel_launch(void* const* d_in, const int* in_sizes, int n_in,
                              void* d_out, int out_size, void* d_ws, size_t ws_size,
                              hipStream_t stream) {
    const float* nf    = (const float*)d_in[0];
    const float* attrs = (const float*)d_in[1];
    const float* eattr = (const float*)d_in[2];
    const float* ee    = (const float*)d_in[3];
    const int*   eidx  = (const int*)d_in[4];
    const float* l1w0  = (const float*)d_in[5];
    const float* l1w1  = (const float*)d_in[6];
    const float* w0    = (const float*)d_in[7];
    const float* w1    = (const float*)d_in[8];
    const float* l2w0  = (const float*)d_in[9];
    const float* l2w1  = (const float*)d_in[10];
    const float* scw0  = (const float*)d_in[11];
    const float* scw1  = (const float*)d_in[12];

    int N = in_sizes[0] / 128;
    int E = in_sizes[3] / 8;
    int nb = (N + 255) / 256;
    int nw = (E + 63) / 64;

    // ws layout: h4 | wf | w1p | cnt | off | cur | bsum | rank | rec(64B) | mn | sb
    float* h4    = (float*)d_ws;                       // N*128
    float* wfp   = h4 + (size_t)N * 128;               // 4096 floats (16 KB)
    float* w1p   = wfp + 4096;                         // 8192
    int*   cnt   = (int*)(w1p + 8192);                 // N
    int*   off   = cnt + N;                            // N+1
    int*   cur   = off + N + 1;                        // N
    int*   bsum  = cur + N;                            // nb
    int*   rank  = bsum + nb;                          // E (16-B aligned below)
    size_t rec_off = (((size_t)((char*)(rank + E) - (char*)d_ws)) + 63) & ~(size_t)63;
    uint4* rec   = (uint4*)((char*)d_ws + rec_off);    // E * 4 uint4 (64 B/edge)
    float* mn    = (float*)(rec + (size_t)E * 4);      // N*256
    float* sb    = mn + (size_t)N * 256;               // nw*512
    size_t need  = (size_t)((char*)(sb + (size_t)nw * 512) - (char*)d_ws);
    bool big = ws_size >= need;

    hipMemsetAsync(cnt, 0, (size_t)N * sizeof(int), stream);
    hist_kernel<<<(E / 4 + 256) / 256, 256, 0, stream>>>(eidx, cnt, rank, E);
    scan_bsum<<<nb, 256, 0, stream>>>(cnt, bsum, N);
    bscan_prep<<<5, 1024, 0, stream>>>(bsum, nb, w1, (uint4*)wfp);
    scan_final<<<nb, 256, 0, stream>>>(cnt, bsum, off, cur, N);

    if (big) {
        int nScat = (E + 255) / 256;
        int nNode = (N + 1) / 2;
        scatnode_kernel<<<nScat + nNode, 256, 0, stream>>>(
            eidx, rank, (const float4*)ee, (const float4*)eattr, off, rec, E, nScat,
            nf, attrs, l1w0, l1w1, scw0, scw1, h4, (float*)d_out, N);
        fused_kernel<<<(E + 255) / 256, 256, 0, stream>>>(rec, (const uint4*)wfp, w0,
                                                          (const float4*)h4,
                                                          mn, sb, E);
        fixlin_kernel<<<(N + 3) / 4, 256, 0, stream>>>(mn, sb, off, l2w0, l2w1,
                                                       (float*)d_out, N);
    } else {
        prep_w1p<<<16, 256, 0, stream>>>(w1, w1p);
        scatter_small<<<(E + 255) / 256, 256, 0, stream>>>(eidx, cur, (int4*)rec, E);
        node_kernel<<<(N + 1) / 2, 256, 0, stream>>>(nf, attrs, l1w0, l1w1, scw0, scw1,
                                                     h4, (float*)d_out, N);
        gather_kernel<<<N, 64, 0, stream>>>(ee, (const float4*)eattr, (const int4*)rec,
                                            off, w0, (const float2*)w1p,
                                            (const float4*)h4,
                                            l2w0, l2w1, (float*)d_out);
    }
}